// Round 1
// baseline (226.912 us; speedup 1.0000x reference)
//
#include <hip/hip_runtime.h>
#include <stdint.h>

// Problem constants
#define T_DIM 2048
#define B_DIM 32
#define DIN   512
#define DOUT  512
#define M_DIM (T_DIM * B_DIM)   // 65536
#define COLS  (B_DIM * DOUT)    // 16384 columns per timestep

#define ALPHA_F 0.36787944117144233f  // exp(-1)

// Scan chunking: 32 chunks of 64 timesteps, 16-step halo (alpha^16 ~ 1.1e-7)
#define CHUNKS   32
#define CHUNK_T  64
#define HALO     16

typedef float  floatx4 __attribute__((ext_vector_type(4)));
typedef __bf16 bf16x8  __attribute__((ext_vector_type(8)));

// pack two fp32 -> two bf16 (RNE) in one u32
__device__ __forceinline__ uint32_t pk2(float a, float b) {
  uint32_t ua = __float_as_uint(a); ua += 0x7fffu + ((ua >> 16) & 1u);
  uint32_t ub = __float_as_uint(b); ub += 0x7fffu + ((ub >> 16) & 1u);
  return (ua >> 16) | (ub & 0xffff0000u);
}

// ---------------------------------------------------------------------------
// GEMM: y[m,n] = sum_k X[m,k] * W[n,k] + bias[n]
// BM=128, BN=128, BK=64; 256 threads = 4 waves (2x2), each wave owns 64x64.
// fp32 global loads -> bf16 convert -> XOR-swizzled LDS -> mfma 16x16x32 bf16.
// Epilogue also mirrors halo rows (t%64 >= 48) into ws for the scan kernel.
// ---------------------------------------------------------------------------
__launch_bounds__(256, 2)
__global__ void gemm_bias_kernel(const float* __restrict__ X,
                                 const float* __restrict__ W,
                                 const float* __restrict__ bias,
                                 float* __restrict__ Y,
                                 float* __restrict__ halo,
                                 int halo_on)
{
  __shared__ __align__(16) uint16_t As[128 * 64];
  __shared__ __align__(16) uint16_t Bs[128 * 64];

  const int tid  = threadIdx.x;
  const int lane = tid & 63;
  const int wave = tid >> 6;
  const int wm   = wave >> 1;   // 0..1
  const int wn   = wave & 1;    // 0..1
  const int r    = lane & 15;
  const int q    = lane >> 4;   // 0..3

  const int m0 = blockIdx.y * 128;
  const int n0 = blockIdx.x * 128;

  floatx4 acc[4][4];
#pragma unroll
  for (int i = 0; i < 4; ++i)
#pragma unroll
    for (int j = 0; j < 4; ++j) {
      floatx4 z = {0.0f, 0.0f, 0.0f, 0.0f};
      acc[i][j] = z;
    }

  for (int kt = 0; kt < DIN / 64; ++kt) {
    const int k0 = kt * 64;

    // ---- stage A and B tiles: 128 rows x 64 cols fp32 each ----
    // 1024 chunks of 8 floats per tile; 256 threads x 4 chunks.
#pragma unroll
    for (int j = 0; j < 4; ++j) {
      const int cid = tid + j * 256;
      const int row = cid >> 3;      // 0..127
      const int c   = cid & 7;       // 16B chunk within row
      const int slot = (c ^ (row & 7)) << 3;  // ushort offset of swizzled 16B slot

      const float* ga = &X[(size_t)(m0 + row) * DIN + k0 + c * 8];
      float4 a0 = *(const float4*)ga;
      float4 a1 = *(const float4*)(ga + 4);
      uint4 pa;
      pa.x = pk2(a0.x, a0.y); pa.y = pk2(a0.z, a0.w);
      pa.z = pk2(a1.x, a1.y); pa.w = pk2(a1.z, a1.w);
      *(uint4*)&As[row * 64 + slot] = pa;

      const float* gb = &W[(size_t)(n0 + row) * DIN + k0 + c * 8];
      float4 b0 = *(const float4*)gb;
      float4 b1 = *(const float4*)(gb + 4);
      uint4 pb;
      pb.x = pk2(b0.x, b0.y); pb.y = pk2(b0.z, b0.w);
      pb.z = pk2(b1.x, b1.y); pb.w = pk2(b1.z, b1.w);
      *(uint4*)&Bs[row * 64 + slot] = pb;
    }
    __syncthreads();

    // ---- compute: 2 k-substeps of K=32, 16 mfma each ----
#pragma unroll
    for (int kk = 0; kk < 2; ++kk) {
      bf16x8 af[4], bfr[4];
#pragma unroll
      for (int mi = 0; mi < 4; ++mi) {
        const int row = wm * 64 + mi * 16 + r;
        const int c   = (kk * 4 + q) ^ (row & 7);
        af[mi] = *(const bf16x8*)&As[row * 64 + (c << 3)];
      }
#pragma unroll
      for (int ni = 0; ni < 4; ++ni) {
        const int row = wn * 64 + ni * 16 + r;
        const int c   = (kk * 4 + q) ^ (row & 7);
        bfr[ni] = *(const bf16x8*)&Bs[row * 64 + (c << 3)];
      }
#pragma unroll
      for (int mi = 0; mi < 4; ++mi)
#pragma unroll
        for (int ni = 0; ni < 4; ++ni)
          acc[mi][ni] = __builtin_amdgcn_mfma_f32_16x16x32_bf16(
              af[mi], bfr[ni], acc[mi][ni], 0, 0, 0);
    }
    __syncthreads();
  }

  // ---- epilogue: +bias, store Y, mirror halo rows into ws ----
#pragma unroll
  for (int ni = 0; ni < 4; ++ni) {
    const int col = n0 + wn * 64 + ni * 16 + r;
    const float bv = bias[col];
#pragma unroll
    for (int mi = 0; mi < 4; ++mi) {
      const int rowm = m0 + wm * 64 + mi * 16 + q * 4;  // 4 consecutive rows
      const int t = rowm >> 5;        // B_DIM = 32
      const int b = rowm & 31;
      const int tloc = t & (CHUNK_T - 1);
      const bool hw = halo_on && (tloc >= CHUNK_T - HALO) && (t < T_DIM - CHUNK_T);
      const size_t hbase = hw
          ? ((size_t)(((t >> 6) + 1) * HALO + (tloc - (CHUNK_T - HALO))) * COLS)
          : 0;
#pragma unroll
      for (int j = 0; j < 4; ++j) {
        const float v = acc[mi][ni][j] + bv;
        Y[(size_t)(rowm + j) * DOUT + col] = v;
        if (hw) halo[hbase + (size_t)(b + j) * DOUT + col] = v;
      }
    }
  }
}

// ---------------------------------------------------------------------------
// Chunked in-place exponential scan along T.
// grid = (COLS/4/256, n_chunks); each thread owns one float4 column group.
// Seed carry from halo (raw y values preserved in ws), then scan the chunk.
// ---------------------------------------------------------------------------
__global__ void scan_kernel(float* __restrict__ Y,
                            const float* __restrict__ halo,
                            int chunk_len)
{
  const int col4 = blockIdx.x * blockDim.x + threadIdx.x;  // 0..4095
  const int c = blockIdx.y;

  float4* Y4 = (float4*)Y;
  const float4* H4 = (const float4*)halo;

  float4 carry = {0.0f, 0.0f, 0.0f, 0.0f};
  if (c > 0) {
#pragma unroll
    for (int h = 0; h < HALO; ++h) {
      float4 v = H4[(size_t)(c * HALO + h) * (COLS / 4) + col4];
      carry.x = fmaf(ALPHA_F, carry.x, v.x);
      carry.y = fmaf(ALPHA_F, carry.y, v.y);
      carry.z = fmaf(ALPHA_F, carry.z, v.z);
      carry.w = fmaf(ALPHA_F, carry.w, v.w);
    }
  }

  size_t idx = (size_t)c * chunk_len * (COLS / 4) + col4;
  float4 ynext = Y4[idx];
  for (int t = 0; t < chunk_len; ++t) {
    float4 y = ynext;
    if (t + 1 < chunk_len) ynext = Y4[idx + (COLS / 4)];  // prefetch before store
    carry.x = fmaf(ALPHA_F, carry.x, y.x);
    carry.y = fmaf(ALPHA_F, carry.y, y.y);
    carry.z = fmaf(ALPHA_F, carry.z, y.z);
    carry.w = fmaf(ALPHA_F, carry.w, y.w);
    Y4[idx] = carry;
    idx += (COLS / 4);
  }
}

// ---------------------------------------------------------------------------
extern "C" void kernel_launch(void* const* d_in, const int* in_sizes, int n_in,
                              void* d_out, int out_size, void* d_ws, size_t ws_size,
                              hipStream_t stream)
{
  const float* X    = (const float*)d_in[0];  // [T, B, DIN]
  const float* W    = (const float*)d_in[1];  // [DOUT, DIN]
  const float* bias = (const float*)d_in[2];  // [DOUT]
  float* Y = (float*)d_out;                   // [T, B, DOUT]
  float* halo = (float*)d_ws;

  const size_t halo_need = (size_t)CHUNKS * HALO * COLS * sizeof(float);  // 32 MiB
  const int halo_on = (ws_size >= halo_need) ? 1 : 0;

  dim3 g1(DOUT / 128, M_DIM / 128);  // (4, 512)
  gemm_bias_kernel<<<g1, 256, 0, stream>>>(X, W, bias, Y, halo, halo_on);

  const int n_chunks = halo_on ? CHUNKS : 1;
  dim3 g2(COLS / 4 / 256, n_chunks);  // (16, 32) or (16, 1)
  scan_kernel<<<g2, 256, 0, stream>>>(Y, halo, T_DIM / n_chunks);
}

// Round 2
// 107.620 us; speedup vs baseline: 2.1085x; 2.1085x over previous
//
#include <hip/hip_runtime.h>
#include <stdint.h>

// Problem constants
#define T_DIM 2048
#define B_DIM 32
#define DIN   512
#define DOUT  512
#define M_DIM (T_DIM * B_DIM)   // 65536
#define COLS  (B_DIM * DOUT)    // 16384 columns per timestep
#define COLS4 (COLS / 4)        // 4096

#define ALPHA_F 0.36787944117144233f  // exp(-1)
#define INV_1MA 1.5819767068693265f   // 1/(1-alpha)

// Scan chunking: 32 chunks of 64 timesteps, 16-step halo (alpha^16 ~ 1.1e-7)
#define CHUNKS   32
#define CHUNK_T  64
#define HALO     16

typedef float  floatx4 __attribute__((ext_vector_type(4)));
typedef __bf16 bf16x8  __attribute__((ext_vector_type(8)));

// pack two fp32 -> two bf16 (RNE) in one u32
__device__ __forceinline__ uint32_t pk2(float a, float b) {
  uint32_t ua = __float_as_uint(a); ua += 0x7fffu + ((ua >> 16) & 1u);
  uint32_t ub = __float_as_uint(b); ub += 0x7fffu + ((ub >> 16) & 1u);
  return (ua >> 16) | (ub & 0xffff0000u);
}

__device__ __forceinline__ void gload_lds16(const void* g, void* lds) {
  __builtin_amdgcn_global_load_lds(
      (const __attribute__((address_space(1))) void*)g,
      (__attribute__((address_space(3))) void*)lds,
      16, 0, 0);
}

// ===========================================================================
// NEW PATH
// ===========================================================================

// ---------------------------------------------------------------------------
// Kernel 1: chunked exponential filter on X (fp32 -> bf16), + W fp32->bf16.
// grid (16, CHUNKS+1) x 256. blockIdx.y == CHUNKS converts W.
// Halo: recompute carry from 16 raw-x steps (alpha^16 truncation ~1e-7).
// ---------------------------------------------------------------------------
__global__ void filter_x_kernel(const float* __restrict__ X,
                                uint16_t* __restrict__ XF,
                                const float* __restrict__ W,
                                uint16_t* __restrict__ WB)
{
  if (blockIdx.y == CHUNKS) {
    // convert W: 262144 floats, 4096 threads x 64
    const int t = blockIdx.x * 256 + threadIdx.x;
    const float4* W4 = (const float4*)W;
#pragma unroll
    for (int j = 0; j < 8; ++j) {
      const int b4 = t * 16 + j * 2;
      float4 w0 = W4[b4], w1 = W4[b4 + 1];
      uint4 p;
      p.x = pk2(w0.x, w0.y); p.y = pk2(w0.z, w0.w);
      p.z = pk2(w1.x, w1.y); p.w = pk2(w1.z, w1.w);
      *(uint4*)&WB[t * 64 + j * 8] = p;
    }
    return;
  }

  const int col4 = blockIdx.x * blockDim.x + threadIdx.x;  // 0..4095
  const int c = blockIdx.y;
  const float4* X4 = (const float4*)X;

  float4 carry = {0.0f, 0.0f, 0.0f, 0.0f};
  if (c > 0) {
    size_t hidx = ((size_t)c * CHUNK_T - HALO) * COLS4 + col4;
#pragma unroll
    for (int h = 0; h < HALO; ++h) {
      float4 v = X4[hidx]; hidx += COLS4;
      carry.x = fmaf(ALPHA_F, carry.x, v.x);
      carry.y = fmaf(ALPHA_F, carry.y, v.y);
      carry.z = fmaf(ALPHA_F, carry.z, v.z);
      carry.w = fmaf(ALPHA_F, carry.w, v.w);
    }
  }

  size_t idx = (size_t)c * CHUNK_T * COLS4 + col4;
  for (int t = 0; t < CHUNK_T; ++t) {
    float4 v = X4[idx];
    carry.x = fmaf(ALPHA_F, carry.x, v.x);
    carry.y = fmaf(ALPHA_F, carry.y, v.y);
    carry.z = fmaf(ALPHA_F, carry.z, v.z);
    carry.w = fmaf(ALPHA_F, carry.w, v.w);
    uint2 p;
    p.x = pk2(carry.x, carry.y);
    p.y = pk2(carry.z, carry.w);
    *(uint2*)&XF[idx * 4] = p;   // elem index == idx*4, 8B aligned
    idx += COLS4;
  }
}

// ---------------------------------------------------------------------------
// Kernel 2: bf16 GEMM (m97 structure): Y[m,n] = XF[m,:]·WB[n,:] + s(t)·bias[n]
// BM=BN=128, BK=64; 256 thr / 4 waves (2x2), 64x64 per wave.
// global_load_lds width16 with PRE-SWIZZLED global source (linear LDS dest),
// XOR-swizzled ds_read_b128 (conflict-free), chunked-bijective XCD swizzle.
// ---------------------------------------------------------------------------
__launch_bounds__(256, 4)
__global__ void gemm_bf16_kernel(const uint16_t* __restrict__ XF,
                                 const uint16_t* __restrict__ WB,
                                 const float* __restrict__ bias,
                                 float* __restrict__ Y)
{
  __shared__ __align__(16) uint16_t As[128 * 64];
  __shared__ __align__(16) uint16_t Bs[128 * 64];

  // chunked XCD swizzle: 2048 blocks, 8 XCDs, 256 per XCD; n fastest within
  const int bid = blockIdx.x;
  const int lg = (bid & 7) * 256 + (bid >> 3);
  const int n0 = (lg & 3) * 128;
  const int m0 = (lg >> 2) * 128;

  const int tid  = threadIdx.x;
  const int lane = tid & 63;
  const int w    = tid >> 6;
  const int r    = lane & 15;
  const int q    = lane >> 4;
  const int wm   = w >> 1;
  const int wn   = w & 1;

  // staging geometry: wave w, instr i covers rows w*32+i*8 .. +7 (1024B)
  const int srow_base = w * 32 + (lane >> 3);   // + i*8
  const int schunk    = lane & 7;

  floatx4 acc[4][4];
#pragma unroll
  for (int i = 0; i < 4; ++i)
#pragma unroll
    for (int j = 0; j < 4; ++j) {
      floatx4 z = {0.0f, 0.0f, 0.0f, 0.0f};
      acc[i][j] = z;
    }

  for (int kt = 0; kt < DIN / 64; ++kt) {
    const int k0 = kt * 64;
#pragma unroll
    for (int i = 0; i < 4; ++i) {
      const int row = srow_base + i * 8;
      // pre-swizzle source chunk so linear LDS write lands swizzled
      const int sc = schunk ^ (row & 7);
      gload_lds16(XF + (size_t)(m0 + row) * DIN + k0 + sc * 8,
                  &As[(w * 32 + i * 8) * 64]);
      gload_lds16(WB + (size_t)(n0 + row) * DIN + k0 + sc * 8,
                  &Bs[(w * 32 + i * 8) * 64]);
    }
    __syncthreads();   // drains vmcnt before reads

#pragma unroll
    for (int kk = 0; kk < 2; ++kk) {
      bf16x8 af[4], bfr[4];
#pragma unroll
      for (int mi = 0; mi < 4; ++mi) {
        const int row = wm * 64 + mi * 16 + r;
        const int cch = (kk * 4 + q) ^ (row & 7);
        af[mi] = *(const bf16x8*)&As[row * 64 + (cch << 3)];
      }
#pragma unroll
      for (int ni = 0; ni < 4; ++ni) {
        const int row = wn * 64 + ni * 16 + r;
        const int cch = (kk * 4 + q) ^ (row & 7);
        bfr[ni] = *(const bf16x8*)&Bs[row * 64 + (cch << 3)];
      }
#pragma unroll
      for (int mi = 0; mi < 4; ++mi)
#pragma unroll
        for (int ni = 0; ni < 4; ++ni)
          acc[mi][ni] = __builtin_amdgcn_mfma_f32_16x16x32_bf16(
              af[mi], bfr[ni], acc[mi][ni], 0, 0, 0);
    }
    __syncthreads();
  }

  // epilogue: + s(t)*bias  where s(t) = (1 - alpha^(t+1)) / (1 - alpha)
#pragma unroll
  for (int mi = 0; mi < 4; ++mi) {
    const int rowb = m0 + wm * 64 + mi * 16;   // 16-row granule, t uniform
    const int t = rowb >> 5;                   // B_DIM = 32
    const float s = (1.0f - __expf(-(float)(t + 1))) * INV_1MA;
#pragma unroll
    for (int ni = 0; ni < 4; ++ni) {
      const int col = n0 + wn * 64 + ni * 16 + r;
      const float sb = s * bias[col];
#pragma unroll
      for (int j = 0; j < 4; ++j)
        Y[(size_t)(rowb + q * 4 + j) * DOUT + col] = acc[mi][ni][j] + sb;
    }
  }
}

// ===========================================================================
// FALLBACK PATH (round-1, used only if ws is too small for the new path)
// ===========================================================================
__launch_bounds__(256, 2)
__global__ void gemm_bias_kernel(const float* __restrict__ X,
                                 const float* __restrict__ W,
                                 const float* __restrict__ bias,
                                 float* __restrict__ Y,
                                 float* __restrict__ halo,
                                 int halo_on)
{
  __shared__ __align__(16) uint16_t As[128 * 64];
  __shared__ __align__(16) uint16_t Bs[128 * 64];

  const int tid  = threadIdx.x;
  const int lane = tid & 63;
  const int wave = tid >> 6;
  const int wm   = wave >> 1;
  const int wn   = wave & 1;
  const int r    = lane & 15;
  const int q    = lane >> 4;

  const int m0 = blockIdx.y * 128;
  const int n0 = blockIdx.x * 128;

  floatx4 acc[4][4];
#pragma unroll
  for (int i = 0; i < 4; ++i)
#pragma unroll
    for (int j = 0; j < 4; ++j) {
      floatx4 z = {0.0f, 0.0f, 0.0f, 0.0f};
      acc[i][j] = z;
    }

  for (int kt = 0; kt < DIN / 64; ++kt) {
    const int k0 = kt * 64;
#pragma unroll
    for (int j = 0; j < 4; ++j) {
      const int cid = tid + j * 256;
      const int row = cid >> 3;
      const int c   = cid & 7;
      const int slot = (c ^ (row & 7)) << 3;

      const float* ga = &X[(size_t)(m0 + row) * DIN + k0 + c * 8];
      float4 a0 = *(const float4*)ga;
      float4 a1 = *(const float4*)(ga + 4);
      uint4 pa;
      pa.x = pk2(a0.x, a0.y); pa.y = pk2(a0.z, a0.w);
      pa.z = pk2(a1.x, a1.y); pa.w = pk2(a1.z, a1.w);
      *(uint4*)&As[row * 64 + slot] = pa;

      const float* gb = &W[(size_t)(n0 + row) * DIN + k0 + c * 8];
      float4 b0 = *(const float4*)gb;
      float4 b1 = *(const float4*)(gb + 4);
      uint4 pb;
      pb.x = pk2(b0.x, b0.y); pb.y = pk2(b0.z, b0.w);
      pb.z = pk2(b1.x, b1.y); pb.w = pk2(b1.z, b1.w);
      *(uint4*)&Bs[row * 64 + slot] = pb;
    }
    __syncthreads();

#pragma unroll
    for (int kk = 0; kk < 2; ++kk) {
      bf16x8 af[4], bfr[4];
#pragma unroll
      for (int mi = 0; mi < 4; ++mi) {
        const int row = wm * 64 + mi * 16 + r;
        const int c   = (kk * 4 + q) ^ (row & 7);
        af[mi] = *(const bf16x8*)&As[row * 64 + (c << 3)];
      }
#pragma unroll
      for (int ni = 0; ni < 4; ++ni) {
        const int row = wn * 64 + ni * 16 + r;
        const int c   = (kk * 4 + q) ^ (row & 7);
        bfr[ni] = *(const bf16x8*)&Bs[row * 64 + (c << 3)];
      }
#pragma unroll
      for (int mi = 0; mi < 4; ++mi)
#pragma unroll
        for (int ni = 0; ni < 4; ++ni)
          acc[mi][ni] = __builtin_amdgcn_mfma_f32_16x16x32_bf16(
              af[mi], bfr[ni], acc[mi][ni], 0, 0, 0);
    }
    __syncthreads();
  }

#pragma unroll
  for (int ni = 0; ni < 4; ++ni) {
    const int col = n0 + wn * 64 + ni * 16 + r;
    const float bv = bias[col];
#pragma unroll
    for (int mi = 0; mi < 4; ++mi) {
      const int rowm = m0 + wm * 64 + mi * 16 + q * 4;
      const int t = rowm >> 5;
      const int b = rowm & 31;
      const int tloc = t & (CHUNK_T - 1);
      const bool hw = halo_on && (tloc >= CHUNK_T - HALO) && (t < T_DIM - CHUNK_T);
      const size_t hbase = hw
          ? ((size_t)(((t >> 6) + 1) * HALO + (tloc - (CHUNK_T - HALO))) * COLS)
          : 0;
#pragma unroll
      for (int j = 0; j < 4; ++j) {
        const float v = acc[mi][ni][j] + bv;
        Y[(size_t)(rowm + j) * DOUT + col] = v;
        if (hw) halo[hbase + (size_t)(b + j) * DOUT + col] = v;
      }
    }
  }
}

__global__ void scan_kernel(float* __restrict__ Y,
                            const float* __restrict__ halo,
                            int chunk_len)
{
  const int col4 = blockIdx.x * blockDim.x + threadIdx.x;
  const int c = blockIdx.y;

  float4* Y4 = (float4*)Y;
  const float4* H4 = (const float4*)halo;

  float4 carry = {0.0f, 0.0f, 0.0f, 0.0f};
  if (c > 0) {
#pragma unroll
    for (int h = 0; h < HALO; ++h) {
      float4 v = H4[(size_t)(c * HALO + h) * COLS4 + col4];
      carry.x = fmaf(ALPHA_F, carry.x, v.x);
      carry.y = fmaf(ALPHA_F, carry.y, v.y);
      carry.z = fmaf(ALPHA_F, carry.z, v.z);
      carry.w = fmaf(ALPHA_F, carry.w, v.w);
    }
  }

  size_t idx = (size_t)c * chunk_len * COLS4 + col4;
  float4 ynext = Y4[idx];
  for (int t = 0; t < chunk_len; ++t) {
    float4 y = ynext;
    if (t + 1 < chunk_len) ynext = Y4[idx + COLS4];
    carry.x = fmaf(ALPHA_F, carry.x, y.x);
    carry.y = fmaf(ALPHA_F, carry.y, y.y);
    carry.z = fmaf(ALPHA_F, carry.z, y.z);
    carry.w = fmaf(ALPHA_F, carry.w, y.w);
    Y4[idx] = carry;
    idx += COLS4;
  }
}

// ---------------------------------------------------------------------------
extern "C" void kernel_launch(void* const* d_in, const int* in_sizes, int n_in,
                              void* d_out, int out_size, void* d_ws, size_t ws_size,
                              hipStream_t stream)
{
  const float* X    = (const float*)d_in[0];  // [T, B, DIN]
  const float* W    = (const float*)d_in[1];  // [DOUT, DIN]
  const float* bias = (const float*)d_in[2];  // [DOUT]
  float* Y = (float*)d_out;                   // [T, B, DOUT]

  const size_t need_new = (size_t)M_DIM * DIN * 2 + (size_t)DOUT * DIN * 2; // 64.5 MiB

  if (ws_size >= need_new) {
    uint16_t* XF = (uint16_t*)d_ws;
    uint16_t* WB = XF + (size_t)M_DIM * DIN;

    dim3 gf(16, CHUNKS + 1);
    filter_x_kernel<<<gf, 256, 0, stream>>>(X, XF, W, WB);

    gemm_bf16_kernel<<<2048, 256, 0, stream>>>(XF, WB, bias, Y);
  } else {
    float* halo = (float*)d_ws;
    const size_t halo_need = (size_t)CHUNKS * HALO * COLS * sizeof(float);
    const int halo_on = (ws_size >= halo_need) ? 1 : 0;

    dim3 g1(DOUT / 128, M_DIM / 128);
    gemm_bias_kernel<<<g1, 256, 0, stream>>>(X, W, bias, Y, halo, halo_on);

    const int n_chunks = halo_on ? CHUNKS : 1;
    dim3 g2(COLS4 / 256, n_chunks);
    scan_kernel<<<g2, 256, 0, stream>>>(Y, halo, T_DIM / n_chunks);
  }
}

// Round 3
// 100.875 us; speedup vs baseline: 2.2494x; 1.0669x over previous
//
#include <hip/hip_runtime.h>
#include <stdint.h>

// Problem constants
#define T_DIM 2048
#define B_DIM 32
#define DIN   512
#define DOUT  512
#define M_DIM (T_DIM * B_DIM)   // 65536
#define COLS  (B_DIM * DIN)     // 16384 lanes per timestep (B*D)
#define COLS4 (COLS / 4)        // 4096

#define ALPHA_F 0.36787944117144233f  // exp(-1)
#define INV_1MA 1.5819767068693265f   // 1/(1-alpha)

// Filter chunking: 64 chunks of 32 timesteps, 16-step halo (alpha^16 ~ 1.1e-7)
#define CHUNKS   64
#define CHUNK_T  32
#define HALO     16

// Fallback-path chunking (round-1)
#define FCHUNKS  32
#define FCHUNK_T 64

typedef float  floatx4 __attribute__((ext_vector_type(4)));
typedef __bf16 bf16x8  __attribute__((ext_vector_type(8)));

// pack two fp32 -> two bf16 (RNE) in one u32
__device__ __forceinline__ uint32_t pk2(float a, float b) {
  uint32_t ua = __float_as_uint(a); ua += 0x7fffu + ((ua >> 16) & 1u);
  uint32_t ub = __float_as_uint(b); ub += 0x7fffu + ((ub >> 16) & 1u);
  return (ua >> 16) | (ub & 0xffff0000u);
}

__device__ __forceinline__ void gload_lds16(const void* g, void* lds) {
  __builtin_amdgcn_global_load_lds(
      (const __attribute__((address_space(1))) void*)g,
      (__attribute__((address_space(3))) void*)lds,
      16, 0, 0);
}

// ===========================================================================
// Kernel 1: chunked exponential filter on X (fp32 -> bf16), + W fp32->bf16.
// grid (16, CHUNKS+1) x 256. blockIdx.y == CHUNKS converts W.
// 8-wide unrolled loads (8 outstanding 16B loads/thread) to hide HBM latency.
// ---------------------------------------------------------------------------
__global__ void filter_x_kernel(const float* __restrict__ X,
                                uint16_t* __restrict__ XF,
                                const float* __restrict__ W,
                                uint16_t* __restrict__ WB)
{
  if (blockIdx.y == CHUNKS) {
    // convert W: 262144 floats, 4096 threads x 64
    const int t = blockIdx.x * 256 + threadIdx.x;
    const float4* W4 = (const float4*)W;
#pragma unroll
    for (int j = 0; j < 8; ++j) {
      const int b4 = t * 16 + j * 2;
      float4 w0 = W4[b4], w1 = W4[b4 + 1];
      uint4 p;
      p.x = pk2(w0.x, w0.y); p.y = pk2(w0.z, w0.w);
      p.z = pk2(w1.x, w1.y); p.w = pk2(w1.z, w1.w);
      *(uint4*)&WB[t * 64 + j * 8] = p;
    }
    return;
  }

  const int col4 = blockIdx.x * blockDim.x + threadIdx.x;  // 0..4095
  const int c = blockIdx.y;
  const float4* X4 = (const float4*)X;

  float4 carry = {0.0f, 0.0f, 0.0f, 0.0f};
  if (c > 0) {
    size_t hidx = ((size_t)c * CHUNK_T - HALO) * COLS4 + col4;
#pragma unroll
    for (int g = 0; g < HALO / 8; ++g) {
      float4 h[8];
#pragma unroll
      for (int j = 0; j < 8; ++j) h[j] = X4[hidx + (size_t)j * COLS4];
#pragma unroll
      for (int j = 0; j < 8; ++j) {
        carry.x = fmaf(ALPHA_F, carry.x, h[j].x);
        carry.y = fmaf(ALPHA_F, carry.y, h[j].y);
        carry.z = fmaf(ALPHA_F, carry.z, h[j].z);
        carry.w = fmaf(ALPHA_F, carry.w, h[j].w);
      }
      hidx += (size_t)8 * COLS4;
    }
  }

  size_t idx = (size_t)c * CHUNK_T * COLS4 + col4;
#pragma unroll 1
  for (int tt = 0; tt < CHUNK_T / 8; ++tt) {
    float4 v[8];
#pragma unroll
    for (int j = 0; j < 8; ++j) v[j] = X4[idx + (size_t)j * COLS4];
#pragma unroll
    for (int j = 0; j < 8; ++j) {
      carry.x = fmaf(ALPHA_F, carry.x, v[j].x);
      carry.y = fmaf(ALPHA_F, carry.y, v[j].y);
      carry.z = fmaf(ALPHA_F, carry.z, v[j].z);
      carry.w = fmaf(ALPHA_F, carry.w, v[j].w);
      uint2 p;
      p.x = pk2(carry.x, carry.y);
      p.y = pk2(carry.z, carry.w);
      *(uint2*)&XF[(idx + (size_t)j * COLS4) * 4] = p;
    }
    idx += (size_t)8 * COLS4;
  }
}

// ---------------------------------------------------------------------------
// Kernel 2: bf16 GEMM (m97 structure): Y[m,n] = XF[m,:]·WB[n,:] + s(t)·bias[n]
// BM=BN=128, BK=64; 256 thr / 4 waves (2x2), 64x64 per wave.
// global_load_lds width16 with PRE-SWIZZLED global source (linear LDS dest),
// XOR-swizzled ds_read_b128 (conflict-free), chunked-bijective XCD swizzle.
// ---------------------------------------------------------------------------
__launch_bounds__(256, 4)
__global__ void gemm_bf16_kernel(const uint16_t* __restrict__ XF,
                                 const uint16_t* __restrict__ WB,
                                 const float* __restrict__ bias,
                                 float* __restrict__ Y)
{
  __shared__ __align__(16) uint16_t As[128 * 64];
  __shared__ __align__(16) uint16_t Bs[128 * 64];

  // chunked XCD swizzle: 2048 blocks, 8 XCDs, 256 per XCD; n fastest within
  const int bid = blockIdx.x;
  const int lg = (bid & 7) * 256 + (bid >> 3);
  const int n0 = (lg & 3) * 128;
  const int m0 = (lg >> 2) * 128;

  const int tid  = threadIdx.x;
  const int lane = tid & 63;
  const int w    = tid >> 6;
  const int r    = lane & 15;
  const int q    = lane >> 4;
  const int wm   = w >> 1;
  const int wn   = w & 1;

  // staging geometry: wave w, instr i covers rows w*32+i*8 .. +7 (1024B)
  const int srow_base = w * 32 + (lane >> 3);   // + i*8
  const int schunk    = lane & 7;

  floatx4 acc[4][4];
#pragma unroll
  for (int i = 0; i < 4; ++i)
#pragma unroll
    for (int j = 0; j < 4; ++j) {
      floatx4 z = {0.0f, 0.0f, 0.0f, 0.0f};
      acc[i][j] = z;
    }

  for (int kt = 0; kt < DIN / 64; ++kt) {
    const int k0 = kt * 64;
#pragma unroll
    for (int i = 0; i < 4; ++i) {
      const int row = srow_base + i * 8;
      // pre-swizzle source chunk so linear LDS write lands swizzled
      const int sc = schunk ^ (row & 7);
      gload_lds16(XF + (size_t)(m0 + row) * DIN + k0 + sc * 8,
                  &As[(w * 32 + i * 8) * 64]);
      gload_lds16(WB + (size_t)(n0 + row) * DIN + k0 + sc * 8,
                  &Bs[(w * 32 + i * 8) * 64]);
    }
    __syncthreads();   // drains vmcnt before reads

#pragma unroll
    for (int kk = 0; kk < 2; ++kk) {
      bf16x8 af[4], bfr[4];
#pragma unroll
      for (int mi = 0; mi < 4; ++mi) {
        const int row = wm * 64 + mi * 16 + r;
        const int cch = (kk * 4 + q) ^ (row & 7);
        af[mi] = *(const bf16x8*)&As[row * 64 + (cch << 3)];
      }
#pragma unroll
      for (int ni = 0; ni < 4; ++ni) {
        const int row = wn * 64 + ni * 16 + r;
        const int cch = (kk * 4 + q) ^ (row & 7);
        bfr[ni] = *(const bf16x8*)&Bs[row * 64 + (cch << 3)];
      }
#pragma unroll
      for (int mi = 0; mi < 4; ++mi)
#pragma unroll
        for (int ni = 0; ni < 4; ++ni)
          acc[mi][ni] = __builtin_amdgcn_mfma_f32_16x16x32_bf16(
              af[mi], bfr[ni], acc[mi][ni], 0, 0, 0);
    }
    __syncthreads();
  }

  // epilogue: + s(t)*bias  where s(t) = (1 - alpha^(t+1)) / (1 - alpha)
#pragma unroll
  for (int mi = 0; mi < 4; ++mi) {
    const int rowb = m0 + wm * 64 + mi * 16;   // 16-row granule, t uniform
    const int t = rowb >> 5;                   // B_DIM = 32
    const float s = (1.0f - __expf(-(float)(t + 1))) * INV_1MA;
#pragma unroll
    for (int ni = 0; ni < 4; ++ni) {
      const int col = n0 + wn * 64 + ni * 16 + r;
      const float sb = s * bias[col];
#pragma unroll
      for (int j = 0; j < 4; ++j)
        Y[(size_t)(rowb + q * 4 + j) * DOUT + col] = acc[mi][ni][j] + sb;
    }
  }
}

// ===========================================================================
// FALLBACK PATH (round-1, used only if ws is too small for the new path)
// ===========================================================================
__launch_bounds__(256, 2)
__global__ void gemm_bias_kernel(const float* __restrict__ X,
                                 const float* __restrict__ W,
                                 const float* __restrict__ bias,
                                 float* __restrict__ Y,
                                 float* __restrict__ halo,
                                 int halo_on)
{
  __shared__ __align__(16) uint16_t As[128 * 64];
  __shared__ __align__(16) uint16_t Bs[128 * 64];

  const int tid  = threadIdx.x;
  const int lane = tid & 63;
  const int wave = tid >> 6;
  const int wm   = wave >> 1;
  const int wn   = wave & 1;
  const int r    = lane & 15;
  const int q    = lane >> 4;

  const int m0 = blockIdx.y * 128;
  const int n0 = blockIdx.x * 128;

  floatx4 acc[4][4];
#pragma unroll
  for (int i = 0; i < 4; ++i)
#pragma unroll
    for (int j = 0; j < 4; ++j) {
      floatx4 z = {0.0f, 0.0f, 0.0f, 0.0f};
      acc[i][j] = z;
    }

  for (int kt = 0; kt < DIN / 64; ++kt) {
    const int k0 = kt * 64;
#pragma unroll
    for (int j = 0; j < 4; ++j) {
      const int cid = tid + j * 256;
      const int row = cid >> 3;
      const int c   = cid & 7;
      const int slot = (c ^ (row & 7)) << 3;

      const float* ga = &X[(size_t)(m0 + row) * DIN + k0 + c * 8];
      float4 a0 = *(const float4*)ga;
      float4 a1 = *(const float4*)(ga + 4);
      uint4 pa;
      pa.x = pk2(a0.x, a0.y); pa.y = pk2(a0.z, a0.w);
      pa.z = pk2(a1.x, a1.y); pa.w = pk2(a1.z, a1.w);
      *(uint4*)&As[row * 64 + slot] = pa;

      const float* gb = &W[(size_t)(n0 + row) * DIN + k0 + c * 8];
      float4 b0 = *(const float4*)gb;
      float4 b1 = *(const float4*)(gb + 4);
      uint4 pb;
      pb.x = pk2(b0.x, b0.y); pb.y = pk2(b0.z, b0.w);
      pb.z = pk2(b1.x, b1.y); pb.w = pk2(b1.z, b1.w);
      *(uint4*)&Bs[row * 64 + slot] = pb;
    }
    __syncthreads();

#pragma unroll
    for (int kk = 0; kk < 2; ++kk) {
      bf16x8 af[4], bfr[4];
#pragma unroll
      for (int mi = 0; mi < 4; ++mi) {
        const int row = wm * 64 + mi * 16 + r;
        const int c   = (kk * 4 + q) ^ (row & 7);
        af[mi] = *(const bf16x8*)&As[row * 64 + (c << 3)];
      }
#pragma unroll
      for (int ni = 0; ni < 4; ++ni) {
        const int row = wn * 64 + ni * 16 + r;
        const int c   = (kk * 4 + q) ^ (row & 7);
        bfr[ni] = *(const bf16x8*)&Bs[row * 64 + (c << 3)];
      }
#pragma unroll
      for (int mi = 0; mi < 4; ++mi)
#pragma unroll
        for (int ni = 0; ni < 4; ++ni)
          acc[mi][ni] = __builtin_amdgcn_mfma_f32_16x16x32_bf16(
              af[mi], bfr[ni], acc[mi][ni], 0, 0, 0);
    }
    __syncthreads();
  }

#pragma unroll
  for (int ni = 0; ni < 4; ++ni) {
    const int col = n0 + wn * 64 + ni * 16 + r;
    const float bv = bias[col];
#pragma unroll
    for (int mi = 0; mi < 4; ++mi) {
      const int rowm = m0 + wm * 64 + mi * 16 + q * 4;
      const int t = rowm >> 5;
      const int b = rowm & 31;
      const int tloc = t & (FCHUNK_T - 1);
      const bool hw = halo_on && (tloc >= FCHUNK_T - HALO) && (t < T_DIM - FCHUNK_T);
      const size_t hbase = hw
          ? ((size_t)(((t >> 6) + 1) * HALO + (tloc - (FCHUNK_T - HALO))) * COLS)
          : 0;
#pragma unroll
      for (int j = 0; j < 4; ++j) {
        const float v = acc[mi][ni][j] + bv;
        Y[(size_t)(rowm + j) * DOUT + col] = v;
        if (hw) halo[hbase + (size_t)(b + j) * DOUT + col] = v;
      }
    }
  }
}

__global__ void scan_kernel(float* __restrict__ Y,
                            const float* __restrict__ halo,
                            int chunk_len)
{
  const int col4 = blockIdx.x * blockDim.x + threadIdx.x;
  const int c = blockIdx.y;

  float4* Y4 = (float4*)Y;
  const float4* H4 = (const float4*)halo;

  float4 carry = {0.0f, 0.0f, 0.0f, 0.0f};
  if (c > 0) {
#pragma unroll
    for (int h = 0; h < HALO; ++h) {
      float4 v = H4[(size_t)(c * HALO + h) * COLS4 + col4];
      carry.x = fmaf(ALPHA_F, carry.x, v.x);
      carry.y = fmaf(ALPHA_F, carry.y, v.y);
      carry.z = fmaf(ALPHA_F, carry.z, v.z);
      carry.w = fmaf(ALPHA_F, carry.w, v.w);
    }
  }

  size_t idx = (size_t)c * chunk_len * COLS4 + col4;
  float4 ynext = Y4[idx];
  for (int t = 0; t < chunk_len; ++t) {
    float4 y = ynext;
    if (t + 1 < chunk_len) ynext = Y4[idx + COLS4];
    carry.x = fmaf(ALPHA_F, carry.x, y.x);
    carry.y = fmaf(ALPHA_F, carry.y, y.y);
    carry.z = fmaf(ALPHA_F, carry.z, y.z);
    carry.w = fmaf(ALPHA_F, carry.w, y.w);
    Y4[idx] = carry;
    idx += COLS4;
  }
}

// ---------------------------------------------------------------------------
extern "C" void kernel_launch(void* const* d_in, const int* in_sizes, int n_in,
                              void* d_out, int out_size, void* d_ws, size_t ws_size,
                              hipStream_t stream)
{
  const float* X    = (const float*)d_in[0];  // [T, B, DIN]
  const float* W    = (const float*)d_in[1];  // [DOUT, DIN]
  const float* bias = (const float*)d_in[2];  // [DOUT]
  float* Y = (float*)d_out;                   // [T, B, DOUT]

  const size_t need_new = (size_t)M_DIM * DIN * 2 + (size_t)DOUT * DIN * 2; // 64.5 MiB

  if (ws_size >= need_new) {
    uint16_t* XF = (uint16_t*)d_ws;
    uint16_t* WB = XF + (size_t)M_DIM * DIN;

    dim3 gf(16, CHUNKS + 1);
    filter_x_kernel<<<gf, 256, 0, stream>>>(X, XF, W, WB);

    gemm_bf16_kernel<<<2048, 256, 0, stream>>>(XF, WB, bias, Y);
  } else {
    float* halo = (float*)d_ws;
    const size_t halo_need = (size_t)FCHUNKS * HALO * COLS * sizeof(float);
    const int halo_on = (ws_size >= halo_need) ? 1 : 0;

    dim3 g1(DOUT / 128, M_DIM / 128);
    gemm_bias_kernel<<<g1, 256, 0, stream>>>(X, W, bias, Y, halo, halo_on);

    const int n_chunks = halo_on ? FCHUNKS : 1;
    dim3 g2(COLS4 / 256, n_chunks);
    scan_kernel<<<g2, 256, 0, stream>>>(Y, halo, T_DIM / n_chunks);
  }
}

// Round 4
// 98.085 us; speedup vs baseline: 2.3134x; 1.0284x over previous
//
#include <hip/hip_runtime.h>
#include <stdint.h>

// Problem constants
#define T_DIM 2048
#define B_DIM 32
#define DIN   512
#define DOUT  512
#define M_DIM (T_DIM * B_DIM)   // 65536
#define COLS  (B_DIM * DIN)     // 16384 lanes per timestep (B*D)
#define COLS4 (COLS / 4)        // 4096

#define ALPHA_F 0.36787944117144233f  // exp(-1)
#define INV_1MA 1.5819767068693265f   // 1/(1-alpha)

// Filter chunking: 128 chunks of 16 timesteps, 8-step halo (alpha^8 ~ 3.4e-4
// on xf; -> ~1e-3 on out after the 512-dot with |w|~0.025 rms, far below the
// bf16-GEMM error floor 0.0156)
#define CHUNKS   128
#define CHUNK_T  16
#define HALO     8

// Fallback-path chunking (round-1)
#define FCHUNKS  32
#define FCHUNK_T 64
#define FHALO    16

typedef float  floatx4 __attribute__((ext_vector_type(4)));
typedef __bf16 bf16x8  __attribute__((ext_vector_type(8)));

// pack two fp32 -> two bf16 (RNE) in one u32
__device__ __forceinline__ uint32_t pk2(float a, float b) {
  uint32_t ua = __float_as_uint(a); ua += 0x7fffu + ((ua >> 16) & 1u);
  uint32_t ub = __float_as_uint(b); ub += 0x7fffu + ((ub >> 16) & 1u);
  return (ua >> 16) | (ub & 0xffff0000u);
}

__device__ __forceinline__ void gload_lds16(const void* g, void* lds) {
  __builtin_amdgcn_global_load_lds(
      (const __attribute__((address_space(1))) void*)g,
      (__attribute__((address_space(3))) void*)lds,
      16, 0, 0);
}

// ===========================================================================
// Kernel 1: chunked exponential filter on X (fp32 -> bf16), + W fp32->bf16.
// grid (16, CHUNKS+1) x 256. blockIdx.y == CHUNKS converts W.
// ALL 24 loads (8 halo + 16 main) issued up front -> single latency exposure.
// ---------------------------------------------------------------------------
__global__ void filter_x_kernel(const float* __restrict__ X,
                                uint16_t* __restrict__ XF,
                                const float* __restrict__ W,
                                uint16_t* __restrict__ WB)
{
  if (blockIdx.y == CHUNKS) {
    // convert W: 262144 floats, 4096 threads x 64
    const int t = blockIdx.x * 256 + threadIdx.x;
    const float4* W4 = (const float4*)W;
#pragma unroll
    for (int j = 0; j < 8; ++j) {
      const int b4 = t * 16 + j * 2;
      float4 w0 = W4[b4], w1 = W4[b4 + 1];
      uint4 p;
      p.x = pk2(w0.x, w0.y); p.y = pk2(w0.z, w0.w);
      p.z = pk2(w1.x, w1.y); p.w = pk2(w1.z, w1.w);
      *(uint4*)&WB[t * 64 + j * 8] = p;
    }
    return;
  }

  const int col4 = blockIdx.x * blockDim.x + threadIdx.x;  // 0..4095
  const int c = blockIdx.y;
  const float4* X4 = (const float4*)X;

  const size_t base = (size_t)c * CHUNK_T * COLS4 + col4;

  float4 h[HALO];
  float4 v[CHUNK_T];

  // issue everything; all addresses independent of the fma chain
  if (c > 0) {
    const size_t hb = base - (size_t)HALO * COLS4;
#pragma unroll
    for (int j = 0; j < HALO; ++j) h[j] = X4[hb + (size_t)j * COLS4];
  }
#pragma unroll
  for (int j = 0; j < CHUNK_T; ++j) v[j] = X4[base + (size_t)j * COLS4];

  float4 carry = {0.0f, 0.0f, 0.0f, 0.0f};
  if (c > 0) {
#pragma unroll
    for (int j = 0; j < HALO; ++j) {
      carry.x = fmaf(ALPHA_F, carry.x, h[j].x);
      carry.y = fmaf(ALPHA_F, carry.y, h[j].y);
      carry.z = fmaf(ALPHA_F, carry.z, h[j].z);
      carry.w = fmaf(ALPHA_F, carry.w, h[j].w);
    }
  }

#pragma unroll
  for (int j = 0; j < CHUNK_T; ++j) {
    carry.x = fmaf(ALPHA_F, carry.x, v[j].x);
    carry.y = fmaf(ALPHA_F, carry.y, v[j].y);
    carry.z = fmaf(ALPHA_F, carry.z, v[j].z);
    carry.w = fmaf(ALPHA_F, carry.w, v[j].w);
    uint2 p;
    p.x = pk2(carry.x, carry.y);
    p.y = pk2(carry.z, carry.w);
    *(uint2*)&XF[(base + (size_t)j * COLS4) * 4] = p;
  }
}

// ---------------------------------------------------------------------------
// Kernel 2: bf16 GEMM (m97 structure): Y[m,n] = XF[m,:]·WB[n,:] + s(t)·bias[n]
// BM=BN=128, BK=64; 256 thr / 4 waves (2x2), 64x64 per wave.
// global_load_lds width16 with PRE-SWIZZLED global source (linear LDS dest),
// XOR-swizzled ds_read_b128 (conflict-free), chunked-bijective XCD swizzle.
// ---------------------------------------------------------------------------
__launch_bounds__(256, 4)
__global__ void gemm_bf16_kernel(const uint16_t* __restrict__ XF,
                                 const uint16_t* __restrict__ WB,
                                 const float* __restrict__ bias,
                                 float* __restrict__ Y)
{
  __shared__ __align__(16) uint16_t As[128 * 64];
  __shared__ __align__(16) uint16_t Bs[128 * 64];

  // chunked XCD swizzle: 2048 blocks, 8 XCDs, 256 per XCD; n fastest within
  const int bid = blockIdx.x;
  const int lg = (bid & 7) * 256 + (bid >> 3);
  const int n0 = (lg & 3) * 128;
  const int m0 = (lg >> 2) * 128;

  const int tid  = threadIdx.x;
  const int lane = tid & 63;
  const int w    = tid >> 6;
  const int r    = lane & 15;
  const int q    = lane >> 4;
  const int wm   = w >> 1;
  const int wn   = w & 1;

  // staging geometry: wave w, instr i covers rows w*32+i*8 .. +7 (1024B)
  const int srow_base = w * 32 + (lane >> 3);   // + i*8
  const int schunk    = lane & 7;

  floatx4 acc[4][4];
#pragma unroll
  for (int i = 0; i < 4; ++i)
#pragma unroll
    for (int j = 0; j < 4; ++j) {
      floatx4 z = {0.0f, 0.0f, 0.0f, 0.0f};
      acc[i][j] = z;
    }

  for (int kt = 0; kt < DIN / 64; ++kt) {
    const int k0 = kt * 64;
#pragma unroll
    for (int i = 0; i < 4; ++i) {
      const int row = srow_base + i * 8;
      // pre-swizzle source chunk so linear LDS write lands swizzled
      const int sc = schunk ^ (row & 7);
      gload_lds16(XF + (size_t)(m0 + row) * DIN + k0 + sc * 8,
                  &As[(w * 32 + i * 8) * 64]);
      gload_lds16(WB + (size_t)(n0 + row) * DIN + k0 + sc * 8,
                  &Bs[(w * 32 + i * 8) * 64]);
    }
    __syncthreads();   // drains vmcnt before reads

#pragma unroll
    for (int kk = 0; kk < 2; ++kk) {
      bf16x8 af[4], bfr[4];
#pragma unroll
      for (int mi = 0; mi < 4; ++mi) {
        const int row = wm * 64 + mi * 16 + r;
        const int cch = (kk * 4 + q) ^ (row & 7);
        af[mi] = *(const bf16x8*)&As[row * 64 + (cch << 3)];
      }
#pragma unroll
      for (int ni = 0; ni < 4; ++ni) {
        const int row = wn * 64 + ni * 16 + r;
        const int cch = (kk * 4 + q) ^ (row & 7);
        bfr[ni] = *(const bf16x8*)&Bs[row * 64 + (cch << 3)];
      }
#pragma unroll
      for (int mi = 0; mi < 4; ++mi)
#pragma unroll
        for (int ni = 0; ni < 4; ++ni)
          acc[mi][ni] = __builtin_amdgcn_mfma_f32_16x16x32_bf16(
              af[mi], bfr[ni], acc[mi][ni], 0, 0, 0);
    }
    __syncthreads();
  }

  // epilogue: + s(t)*bias  where s(t) = (1 - alpha^(t+1)) / (1 - alpha)
#pragma unroll
  for (int mi = 0; mi < 4; ++mi) {
    const int rowb = m0 + wm * 64 + mi * 16;   // 16-row granule, t uniform
    const int t = rowb >> 5;                   // B_DIM = 32
    const float s = (1.0f - __expf(-(float)(t + 1))) * INV_1MA;
#pragma unroll
    for (int ni = 0; ni < 4; ++ni) {
      const int col = n0 + wn * 64 + ni * 16 + r;
      const float sb = s * bias[col];
#pragma unroll
      for (int j = 0; j < 4; ++j)
        Y[(size_t)(rowb + q * 4 + j) * DOUT + col] = acc[mi][ni][j] + sb;
    }
  }
}

// ===========================================================================
// FALLBACK PATH (round-1, used only if ws is too small for the new path)
// ===========================================================================
__launch_bounds__(256, 2)
__global__ void gemm_bias_kernel(const float* __restrict__ X,
                                 const float* __restrict__ W,
                                 const float* __restrict__ bias,
                                 float* __restrict__ Y,
                                 float* __restrict__ halo,
                                 int halo_on)
{
  __shared__ __align__(16) uint16_t As[128 * 64];
  __shared__ __align__(16) uint16_t Bs[128 * 64];

  const int tid  = threadIdx.x;
  const int lane = tid & 63;
  const int wave = tid >> 6;
  const int wm   = wave >> 1;
  const int wn   = wave & 1;
  const int r    = lane & 15;
  const int q    = lane >> 4;

  const int m0 = blockIdx.y * 128;
  const int n0 = blockIdx.x * 128;

  floatx4 acc[4][4];
#pragma unroll
  for (int i = 0; i < 4; ++i)
#pragma unroll
    for (int j = 0; j < 4; ++j) {
      floatx4 z = {0.0f, 0.0f, 0.0f, 0.0f};
      acc[i][j] = z;
    }

  for (int kt = 0; kt < DIN / 64; ++kt) {
    const int k0 = kt * 64;
#pragma unroll
    for (int j = 0; j < 4; ++j) {
      const int cid = tid + j * 256;
      const int row = cid >> 3;
      const int c   = cid & 7;
      const int slot = (c ^ (row & 7)) << 3;

      const float* ga = &X[(size_t)(m0 + row) * DIN + k0 + c * 8];
      float4 a0 = *(const float4*)ga;
      float4 a1 = *(const float4*)(ga + 4);
      uint4 pa;
      pa.x = pk2(a0.x, a0.y); pa.y = pk2(a0.z, a0.w);
      pa.z = pk2(a1.x, a1.y); pa.w = pk2(a1.z, a1.w);
      *(uint4*)&As[row * 64 + slot] = pa;

      const float* gb = &W[(size_t)(n0 + row) * DIN + k0 + c * 8];
      float4 b0 = *(const float4*)gb;
      float4 b1 = *(const float4*)(gb + 4);
      uint4 pb;
      pb.x = pk2(b0.x, b0.y); pb.y = pk2(b0.z, b0.w);
      pb.z = pk2(b1.x, b1.y); pb.w = pk2(b1.z, b1.w);
      *(uint4*)&Bs[row * 64 + slot] = pb;
    }
    __syncthreads();

#pragma unroll
    for (int kk = 0; kk < 2; ++kk) {
      bf16x8 af[4], bfr[4];
#pragma unroll
      for (int mi = 0; mi < 4; ++mi) {
        const int row = wm * 64 + mi * 16 + r;
        const int c   = (kk * 4 + q) ^ (row & 7);
        af[mi] = *(const bf16x8*)&As[row * 64 + (c << 3)];
      }
#pragma unroll
      for (int ni = 0; ni < 4; ++ni) {
        const int row = wn * 64 + ni * 16 + r;
        const int c   = (kk * 4 + q) ^ (row & 7);
        bfr[ni] = *(const bf16x8*)&Bs[row * 64 + (c << 3)];
      }
#pragma unroll
      for (int mi = 0; mi < 4; ++mi)
#pragma unroll
        for (int ni = 0; ni < 4; ++ni)
          acc[mi][ni] = __builtin_amdgcn_mfma_f32_16x16x32_bf16(
              af[mi], bfr[ni], acc[mi][ni], 0, 0, 0);
    }
    __syncthreads();
  }

#pragma unroll
  for (int ni = 0; ni < 4; ++ni) {
    const int col = n0 + wn * 64 + ni * 16 + r;
    const float bv = bias[col];
#pragma unroll
    for (int mi = 0; mi < 4; ++mi) {
      const int rowm = m0 + wm * 64 + mi * 16 + q * 4;
      const int t = rowm >> 5;
      const int b = rowm & 31;
      const int tloc = t & (FCHUNK_T - 1);
      const bool hw = halo_on && (tloc >= FCHUNK_T - FHALO) && (t < T_DIM - FCHUNK_T);
      const size_t hbase = hw
          ? ((size_t)(((t >> 6) + 1) * FHALO + (tloc - (FCHUNK_T - FHALO))) * COLS)
          : 0;
#pragma unroll
      for (int j = 0; j < 4; ++j) {
        const float v = acc[mi][ni][j] + bv;
        Y[(size_t)(rowm + j) * DOUT + col] = v;
        if (hw) halo[hbase + (size_t)(b + j) * DOUT + col] = v;
      }
    }
  }
}

__global__ void scan_kernel(float* __restrict__ Y,
                            const float* __restrict__ halo,
                            int chunk_len)
{
  const int col4 = blockIdx.x * blockDim.x + threadIdx.x;
  const int c = blockIdx.y;

  float4* Y4 = (float4*)Y;
  const float4* H4 = (const float4*)halo;

  float4 carry = {0.0f, 0.0f, 0.0f, 0.0f};
  if (c > 0) {
#pragma unroll
    for (int h = 0; h < FHALO; ++h) {
      float4 v = H4[(size_t)(c * FHALO + h) * COLS4 + col4];
      carry.x = fmaf(ALPHA_F, carry.x, v.x);
      carry.y = fmaf(ALPHA_F, carry.y, v.y);
      carry.z = fmaf(ALPHA_F, carry.z, v.z);
      carry.w = fmaf(ALPHA_F, carry.w, v.w);
    }
  }

  size_t idx = (size_t)c * chunk_len * COLS4 + col4;
  float4 ynext = Y4[idx];
  for (int t = 0; t < chunk_len; ++t) {
    float4 y = ynext;
    if (t + 1 < chunk_len) ynext = Y4[idx + COLS4];
    carry.x = fmaf(ALPHA_F, carry.x, y.x);
    carry.y = fmaf(ALPHA_F, carry.y, y.y);
    carry.z = fmaf(ALPHA_F, carry.z, y.z);
    carry.w = fmaf(ALPHA_F, carry.w, y.w);
    Y4[idx] = carry;
    idx += COLS4;
  }
}

// ---------------------------------------------------------------------------
extern "C" void kernel_launch(void* const* d_in, const int* in_sizes, int n_in,
                              void* d_out, int out_size, void* d_ws, size_t ws_size,
                              hipStream_t stream)
{
  const float* X    = (const float*)d_in[0];  // [T, B, DIN]
  const float* W    = (const float*)d_in[1];  // [DOUT, DIN]
  const float* bias = (const float*)d_in[2];  // [DOUT]
  float* Y = (float*)d_out;                   // [T, B, DOUT]

  const size_t need_new = (size_t)M_DIM * DIN * 2 + (size_t)DOUT * DIN * 2; // 64.5 MiB

  if (ws_size >= need_new) {
    uint16_t* XF = (uint16_t*)d_ws;
    uint16_t* WB = XF + (size_t)M_DIM * DIN;

    dim3 gf(16, CHUNKS + 1);
    filter_x_kernel<<<gf, 256, 0, stream>>>(X, XF, W, WB);

    gemm_bf16_kernel<<<2048, 256, 0, stream>>>(XF, WB, bias, Y);
  } else {
    float* halo = (float*)d_ws;
    const size_t halo_need = (size_t)FCHUNKS * FHALO * COLS * sizeof(float);
    const int halo_on = (ws_size >= halo_need) ? 1 : 0;

    dim3 g1(DOUT / 128, M_DIM / 128);
    gemm_bias_kernel<<<g1, 256, 0, stream>>>(X, W, bias, Y, halo, halo_on);

    const int n_chunks = halo_on ? FCHUNKS : 1;
    dim3 g2(COLS4 / 256, n_chunks);
    scan_kernel<<<g2, 256, 0, stream>>>(Y, halo, T_DIM / n_chunks);
  }
}